// Round 3
// baseline (96.970 us; speedup 1.0000x reference)
//
#include <hip/hip_runtime.h>
#include <math.h>

#define B_   2
#define C_   3
#define HW_  1024
#define N_   4096
#define AC_  12

#define PI_F    3.14159265358979323846f
#define L2E     1.4426950408889634f   // log2(e)
#define INV_L2E 0.6931471805599453f   // ln(2)

#define OUT0_ELEMS 24576   // B*A*C*H*W
#define OUT1_ELEMS 57344   // B*A*7*H*W
#define OUT2_ELEMS 18432   // B*C*3*H*W

// Fused single-kernel, workspace-free. Each main block owns 16 output rows
// and sweeps ALL 4096 j's via double-buffered LDS tiles. KEY CHANGE vs r2:
// 4 rows per thread -> the 3 ds_read_b128 per j amortize over 4 pairs
// (LDS pipe was the largest single pipe load at 1 row/thread), and 4
// independent dep chains hide exp2/rcp latency. The 4 contiguous rows of a
// thread share hw = i>>2, so p0 is one set of 3 regs, not 12.
#define ROWBLK   16
#define RPT      4
#define JTILE    512
#define NTILE    8                    // N_ / JTILE
#define MAINBLKS 512                  // B_ * (N_ / ROWBLK)
#define CPBLKS   32
#define CP_F4_BBOX 14336              // OUT1_ELEMS/4
#define CP_F4_TOT  18944              // (OUT1+OUT2)/4

#if __has_builtin(__builtin_amdgcn_exp2f)
#define EXP2F(x) __builtin_amdgcn_exp2f(x)
#else
#define EXP2F(x) __expf((x) * INV_L2E)
#endif

// Decode one row of `decoded` into a BEV corner box (x1,y1,x2,y2).
__device__ __forceinline__ float4 make_box(const float* __restrict__ d) {
    float x = d[0], y = d[1], d3 = d[3], d4 = d[4], rot = d[6];
    float kq = floorf(rot / PI_F + 0.5f);
    float normed = fabsf(rot - kq * PI_F);
    bool swap_wh = normed > (0.25f * PI_F);
    float w = swap_wh ? d4 : d3;
    float h = swap_wh ? d3 : d4;
    return make_float4(x - 0.5f * w, y - 0.5f * h, x + 0.5f * w, y + 0.5f * h);
}

// grid 544 x 512:
//   blocks [0,512): 16 rows (4/thread) x all-j fused aggregation.
//     r = t&3 (row slot -> rows 4r..4r+3), q = t>>2 (128 j-subgroups; a wave
//     spans 16 consecutive q -> 16 distinct float4 = 256B contiguous per
//     ds_read_b128 -> 2-way bank aliasing = free; 4 lanes broadcast each).
//   blocks [512,544): float4 passthrough copies of outputs 1 and 2.
// Softmax max-shifts dropped (cancel in num/(den*S)); values safe in f32.
__global__ __launch_bounds__(512, 4) void k_fused(
    const float* __restrict__ scores, const float* __restrict__ pp,
    const float* __restrict__ dec, const float* __restrict__ bbox,
    float* __restrict__ out)
{
    const int blk = blockIdx.x;
    const int t = threadIdx.x;

    if (blk >= MAINBLKS) {
        const float4* src1 = (const float4*)bbox;
        const float4* src2 = (const float4*)pp;
        float4* dst1 = (float4*)(out + OUT0_ELEMS);
        float4* dst2 = (float4*)(out + OUT0_ELEMS + OUT1_ELEMS);
        for (int u = (blk - MAINBLKS) * 512 + t; u < CP_F4_TOT;
             u += CPBLKS * 512) {
            if (u < CP_F4_BBOX) dst1[u] = src1[u];
            else                dst2[u - CP_F4_BBOX] = src2[u - CP_F4_BBOX];
        }
        return;
    }

    const int b = blk >> 8;          // 256 row-blocks per batch
    const int rowblk = blk & 255;
    const int r = t & 3;
    const int q = t >> 2;            // [0,128)

    const float* __restrict__ decb = dec + b * (N_ * 7);
    const float* __restrict__ scb  = scores + b * (AC_ * HW_);
    const float* __restrict__ ppb  = pp + b * (9 * HW_);

    __shared__ float4 s_box[2][JTILE];              // {x1,y1,x2,y2}
    __shared__ float4 s_aux[2][JTILE];              // {area*ln2, e0, e1, e2}
    __shared__ float4 s_p1 [2][JTILE];              // {p1_c0,p1_c1,p1_c2,-}
    __shared__ float2 s_red[8][ROWBLK][C_];         // wave, row, class
    __shared__ float  s_Sp[8][C_];                  // per-wave S partials

    // ---- row setup: 4 contiguous rows, shared hw -> one p0 triple ----
    const int i0 = rowblk * ROWBLK + (r << 2);
    const int hw0 = i0 >> 2;                        // = rowblk*4 + r
    float4 bx[RPT]; float ar[RPT];
#pragma unroll
    for (int k = 0; k < RPT; ++k) {
        bx[k] = make_box(decb + (i0 + k) * 7);
        ar[k] = (bx[k].z - bx[k].x) * (bx[k].w - bx[k].y) * INV_L2E;
    }
    const float p0x = ppb[0 * HW_ + hw0] * L2E;
    const float p0y = ppb[3 * HW_ + hw0] * L2E;
    const float p0z = ppb[6 * HW_ + hw0] * L2E;

    float accn[RPT][C_] = {}, accd[RPT][C_] = {};
    float sS0 = 0.f, sS1 = 0.f, sS2 = 0.f;

    // staging registers (1 j per thread per tile)
    float ld0, ld1, ld3, ld4, ld6, ls0, ls1, ls2, lp1a, lp1b, lp1c;

    {   // prologue: load + decode + publish tile 0
        const float* dj = decb + t * 7;
        ld0 = dj[0]; ld1 = dj[1]; ld3 = dj[3]; ld4 = dj[4]; ld6 = dj[6];
        const int hw = t >> 2, a = t & 3;
        ls0 = scb[(a * C_ + 0) * HW_ + hw];
        ls1 = scb[(a * C_ + 1) * HW_ + hw];
        ls2 = scb[(a * C_ + 2) * HW_ + hw];
        lp1a = ppb[1 * HW_ + hw]; lp1b = ppb[4 * HW_ + hw]; lp1c = ppb[7 * HW_ + hw];
        float kq = floorf(ld6 / PI_F + 0.5f);
        float nr = fabsf(ld6 - kq * PI_F);
        bool sw = nr > (0.25f * PI_F);
        float w = sw ? ld4 : ld3, h = sw ? ld3 : ld4;
        float4 box = make_float4(ld0 - 0.5f * w, ld1 - 0.5f * h,
                                 ld0 + 0.5f * w, ld1 + 0.5f * h);
        float area = (box.z - box.x) * (box.w - box.y);
        float e0 = __expf(ls0), e1 = __expf(ls1), e2 = __expf(ls2);
        sS0 += e0; sS1 += e1; sS2 += e2;
        s_box[0][t] = box;
        s_aux[0][t] = make_float4(area * INV_L2E, e0, e1, e2);
        s_p1 [0][t] = make_float4(lp1a, lp1b, lp1c, 0.f);
    }
    __syncthreads();

#pragma unroll 1
    for (int tile = 0; tile < NTILE; ++tile) {
        const int cur = tile & 1;
        if (tile + 1 < NTILE) {      // issue next-tile global loads early
            const int j = (tile + 1) * JTILE + t;
            const float* dj = decb + j * 7;
            ld0 = dj[0]; ld1 = dj[1]; ld3 = dj[3]; ld4 = dj[4]; ld6 = dj[6];
            const int hw = j >> 2, a = j & 3;
            ls0 = scb[(a * C_ + 0) * HW_ + hw];
            ls1 = scb[(a * C_ + 1) * HW_ + hw];
            ls2 = scb[(a * C_ + 2) * HW_ + hw];
            lp1a = ppb[1 * HW_ + hw]; lp1b = ppb[4 * HW_ + hw]; lp1c = ppb[7 * HW_ + hw];
        }
#pragma unroll 2
        for (int m = 0; m < JTILE / 128; ++m) {
            const int jj = q + (m << 7);
            const float4 bj = s_box[cur][jj];
            const float4 ax = s_aux[cur][jj];   // {area_j*ln2, e0, e1, e2}
            const float4 pj = s_p1 [cur][jj];
#pragma unroll
            for (int k = 0; k < RPT; ++k) {
                float x1 = fmaxf(bx[k].x, bj.x), y1 = fmaxf(bx[k].y, bj.y);
                float x2 = fminf(bx[k].z, bj.z), y2 = fminf(bx[k].w, bj.w);
                float w = fmaxf(x2 - x1, 0.f), h = fmaxf(y2 - y1, 0.f);
                float inter = w * h;
                float uni = fmaf(inter, -INV_L2E, ar[k] + ax.x);   // ln2*union
                float iou = inter * __builtin_amdgcn_rcpf(uni);    // iou*log2e
                float e0 = EXP2F(fmaf(p0x, pj.x, iou));
                float e1 = EXP2F(fmaf(p0y, pj.y, iou));
                float e2 = EXP2F(fmaf(p0z, pj.z, iou));
                accn[k][0] = fmaf(e0, ax.y, accn[k][0]); accd[k][0] += e0;
                accn[k][1] = fmaf(e1, ax.z, accn[k][1]); accd[k][1] += e1;
                accn[k][2] = fmaf(e2, ax.w, accn[k][2]); accd[k][2] += e2;
            }
        }
        if (tile + 1 < NTILE) {      // decode + publish next tile (other buf)
            float kq = floorf(ld6 / PI_F + 0.5f);
            float nr = fabsf(ld6 - kq * PI_F);
            bool sw = nr > (0.25f * PI_F);
            float w = sw ? ld4 : ld3, h = sw ? ld3 : ld4;
            float4 box = make_float4(ld0 - 0.5f * w, ld1 - 0.5f * h,
                                     ld0 + 0.5f * w, ld1 + 0.5f * h);
            float area = (box.z - box.x) * (box.w - box.y);
            float e0 = __expf(ls0), e1 = __expf(ls1), e2 = __expf(ls2);
            sS0 += e0; sS1 += e1; sS2 += e2;
            const int nxt = cur ^ 1;
            s_box[nxt][t] = box;
            s_aux[nxt][t] = make_float4(area * INV_L2E, e0, e1, e2);
            s_p1 [nxt][t] = make_float4(lp1a, lp1b, lp1c, 0.f);
        }
        __syncthreads();
    }

    // ---- reduce the 16 q-lanes (lane bits 2..5) inside each wave ----
#pragma unroll
    for (int k = 0; k < RPT; ++k)
#pragma unroll
        for (int c = 0; c < C_; ++c) {
            float nv = accn[k][c], dv = accd[k][c];
            nv += __shfl_xor(nv, 4);  dv += __shfl_xor(dv, 4);
            nv += __shfl_xor(nv, 8);  dv += __shfl_xor(dv, 8);
            nv += __shfl_xor(nv, 16); dv += __shfl_xor(dv, 16);
            nv += __shfl_xor(nv, 32); dv += __shfl_xor(dv, 32);
            accn[k][c] = nv; accd[k][c] = dv;
        }
    const int wv = t >> 6, lane = t & 63;
    if (lane < 4) {                   // lane == row slot r
#pragma unroll
        for (int k = 0; k < RPT; ++k)
#pragma unroll
            for (int c = 0; c < C_; ++c)
                s_red[wv][(lane << 2) + k][c] =
                    make_float2(accn[k][c], accd[k][c]);
    }
#pragma unroll
    for (int off = 1; off < 64; off <<= 1) {
        sS0 += __shfl_xor(sS0, off);
        sS1 += __shfl_xor(sS1, off);
        sS2 += __shfl_xor(sS2, off);
    }
    if (lane == 0) { s_Sp[wv][0] = sS0; s_Sp[wv][1] = sS1; s_Sp[wv][2] = sS2; }
    __syncthreads();

    // ---- final: 48 (row,c) outputs per block ----
    if (t < C_ * ROWBLK) {
        const int c = t >> 4, row = t & 15;
        float num = 0.f, den = 0.f, S = 0.f;
#pragma unroll
        for (int w = 0; w < 8; ++w) {
            float2 v = s_red[w][row][c];
            num += v.x; den += v.y;
            S += s_Sp[w][c];
        }
        const int n = rowblk * ROWBLK + row;
        out[(b * AC_ + (n & 3) * C_ + c) * HW_ + (n >> 2)] = num / (den * S);
    }
}

extern "C" void kernel_launch(void* const* d_in, const int* in_sizes, int n_in,
                              void* d_out, int out_size, void* d_ws, size_t ws_size,
                              hipStream_t stream) {
    (void)d_ws; (void)ws_size;
    const float* scores = (const float*)d_in[0];
    const float* bbox   = (const float*)d_in[1];
    const float* pp     = (const float*)d_in[2];
    const float* dec    = (const float*)d_in[3];
    k_fused<<<MAINBLKS + CPBLKS, 512, 0, stream>>>(
        scores, pp, dec, bbox, (float*)d_out);
}

// Round 4
// 85.637 us; speedup vs baseline: 1.1323x; 1.1323x over previous
//
#include <hip/hip_runtime.h>
#include <math.h>

#define B_   2
#define C_   3
#define HW_  1024
#define N_   4096
#define AC_  12

#define PI_F    3.14159265358979323846f
#define L2E     1.4426950408889634f   // log2(e)
#define INV_L2E 0.6931471805599453f   // ln(2)

#define OUT0_ELEMS 24576   // B*A*C*H*W
#define OUT1_ELEMS 57344   // B*A*7*H*W
#define OUT2_ELEMS 18432   // B*C*3*H*W

// Fused single-kernel, workspace-free. KEY CHANGE vs r3 (issue-bound on
// VALU+trans): factor exp(iou + p0*p1) = exp(iou) * exp(p0*p1).
//  - exp(iou) is CLASS-INDEPENDENT -> 1 exp2/pair instead of 3.
//  - exp(p0*p1) is constant over the 4x4 (a_i, a_j) anchor block sharing
//    (hw_i, hw_j) -> 3 exp2 per j-QUAD, amortized over 8 pairs.
//  - quad-local sums (Eq, t_c) folded once per quad: per-pair accum is
//    1 add + 3 fma instead of 3 fma + 3 add.
// Per-pair issue cost ~78cy -> ~53cy. Skeleton = proven r1/r2 single-buffer
// LDS with register prefetch; 2 rows/thread = (2r, 2r+1) share hw_i.
#define ROWBLK   32
#define JTILE    512
#define QTILE    128                  // quads per tile
#define NTILE    8                    // N_ / JTILE
#define MAINBLKS 256                  // B_ * (N_ / ROWBLK)
#define CPBLKS   32
#define CP_F4_BBOX 14336              // OUT1_ELEMS/4
#define CP_F4_TOT  18944              // (OUT1+OUT2)/4

#if __has_builtin(__builtin_amdgcn_exp2f)
#define EXP2F(x) __builtin_amdgcn_exp2f(x)
#else
#define EXP2F(x) __expf((x) * INV_L2E)
#endif

// Decode one row of `decoded` into a BEV corner box (x1,y1,x2,y2).
__device__ __forceinline__ float4 make_box(const float* __restrict__ d) {
    float x = d[0], y = d[1], d3 = d[3], d4 = d[4], rot = d[6];
    float kq = floorf(rot / PI_F + 0.5f);
    float normed = fabsf(rot - kq * PI_F);
    bool swap_wh = normed > (0.25f * PI_F);
    float w = swap_wh ? d4 : d3;
    float h = swap_wh ? d3 : d4;
    return make_float4(x - 0.5f * w, y - 0.5f * h, x + 0.5f * w, y + 0.5f * h);
}

// grid 288 x 512:
//   blocks [0,256): 32 rows (2/thread, sharing hw_i) x all-j aggregation.
//     r = t&15 (row slot -> rows 2r,2r+1), q = t>>4 (32 quad-subgroups).
//     Quads u = q + 32*mm; j = 4u..4u+3. A wave covers 4 q values ->
//     4 distinct 16B LDS lines per read (broadcast x16 lanes), conflict-free.
//   blocks [256,288): float4 passthrough copies of outputs 1 and 2.
// Softmax max-shifts dropped (cancel in num/(den*S)); values safe in f32.
__global__ __launch_bounds__(512) void k_fused(
    const float* __restrict__ scores, const float* __restrict__ pp,
    const float* __restrict__ dec, const float* __restrict__ bbox,
    float* __restrict__ out)
{
    const int blk = blockIdx.x;
    const int t = threadIdx.x;

    if (blk >= MAINBLKS) {
        const float4* src1 = (const float4*)bbox;
        const float4* src2 = (const float4*)pp;
        float4* dst1 = (float4*)(out + OUT0_ELEMS);
        float4* dst2 = (float4*)(out + OUT0_ELEMS + OUT1_ELEMS);
        for (int u = (blk - MAINBLKS) * 512 + t; u < CP_F4_TOT;
             u += CPBLKS * 512) {
            if (u < CP_F4_BBOX) dst1[u] = src1[u];
            else                dst2[u - CP_F4_BBOX] = src2[u - CP_F4_BBOX];
        }
        return;
    }

    const int b = blk >> 7;          // 128 row-blocks per batch
    const int rowblk = blk & 127;
    const int r = t & 15;
    const int q = t >> 4;            // [0,32)

    const float* __restrict__ decb = dec + b * (N_ * 7);
    const float* __restrict__ scb  = scores + b * (AC_ * HW_);
    const float* __restrict__ ppb  = pp + b * (9 * HW_);

    __shared__ float4 s_box[JTILE];                 // {x1,y1,x2,y2}
    __shared__ float4 s_aux[JTILE];                 // {area*ln2, e0, e1, e2}
    __shared__ float4 s_p1q[QTILE];                 // per-QUAD {p1_c0,c1,c2,-}
    __shared__ float2 s_red[8][ROWBLK][C_];         // wave, row, class
    __shared__ float  s_Sp[8][C_];                  // per-wave S partials

    // ---- row setup: rows 2r, 2r+1 share hw -> one p0 triple, one g set ----
    const int i0 = rowblk * ROWBLK + (r << 1);
    const float4 bx0 = make_box(decb + i0 * 7);
    const float4 bx1 = make_box(decb + (i0 + 1) * 7);
    const float ar0 = (bx0.z - bx0.x) * (bx0.w - bx0.y) * INV_L2E;
    const float ar1 = (bx1.z - bx1.x) * (bx1.w - bx1.y) * INV_L2E;
    const int hw0 = i0 >> 2;
    const float p0x = ppb[0 * HW_ + hw0] * L2E;
    const float p0y = ppb[3 * HW_ + hw0] * L2E;
    const float p0z = ppb[6 * HW_ + hw0] * L2E;

    float accn[2][C_] = {}, accd[2][C_] = {};
    float sS0 = 0.f, sS1 = 0.f, sS2 = 0.f;

    // staging registers (1 j per thread; threads <128 also stage a p1-quad)
    float ld0, ld1, ld3, ld4, ld6, ls0, ls1, ls2, lq1a = 0.f, lq1b = 0.f, lq1c = 0.f;
    {   // preload tile 0
        const float* dj = decb + t * 7;
        ld0 = dj[0]; ld1 = dj[1]; ld3 = dj[3]; ld4 = dj[4]; ld6 = dj[6];
        const int hw = t >> 2, a = t & 3;
        ls0 = scb[(a * C_ + 0) * HW_ + hw];
        ls1 = scb[(a * C_ + 1) * HW_ + hw];
        ls2 = scb[(a * C_ + 2) * HW_ + hw];
        if (t < QTILE) {
            lq1a = ppb[1 * HW_ + t]; lq1b = ppb[4 * HW_ + t]; lq1c = ppb[7 * HW_ + t];
        }
    }

    for (int tile = 0; tile < NTILE; ++tile) {
        if (tile) __syncthreads();       // prior tile's readers done
        {   // decode + publish staged tile; accumulate S (each j once/block)
            float kq = floorf(ld6 / PI_F + 0.5f);
            float nr = fabsf(ld6 - kq * PI_F);
            bool sw = nr > (0.25f * PI_F);
            float w = sw ? ld4 : ld3, h = sw ? ld3 : ld4;
            float4 box = make_float4(ld0 - 0.5f * w, ld1 - 0.5f * h,
                                     ld0 + 0.5f * w, ld1 + 0.5f * h);
            float area = (box.z - box.x) * (box.w - box.y);
            float e0 = __expf(ls0), e1 = __expf(ls1), e2 = __expf(ls2);
            sS0 += e0; sS1 += e1; sS2 += e2;
            s_box[t] = box;
            s_aux[t] = make_float4(area * INV_L2E, e0, e1, e2);
            if (t < QTILE) s_p1q[t] = make_float4(lq1a, lq1b, lq1c, 0.f);
        }
        __syncthreads();
        if (tile + 1 < NTILE) {          // prefetch next tile under compute
            const int j = (tile + 1) * JTILE + t;
            const float* dj = decb + j * 7;
            ld0 = dj[0]; ld1 = dj[1]; ld3 = dj[3]; ld4 = dj[4]; ld6 = dj[6];
            const int hw = j >> 2, a = j & 3;
            ls0 = scb[(a * C_ + 0) * HW_ + hw];
            ls1 = scb[(a * C_ + 1) * HW_ + hw];
            ls2 = scb[(a * C_ + 2) * HW_ + hw];
            if (t < QTILE) {
                const int uq = (tile + 1) * QTILE + t;
                lq1a = ppb[1 * HW_ + uq]; lq1b = ppb[4 * HW_ + uq]; lq1c = ppb[7 * HW_ + uq];
            }
        }
#pragma unroll
        for (int mm = 0; mm < QTILE / 32; ++mm) {
            const int u = q + (mm << 5);
            const float4 pq = s_p1q[u];
            const float g0 = EXP2F(p0x * pq.x);
            const float g1 = EXP2F(p0y * pq.y);
            const float g2 = EXP2F(p0z * pq.z);
            float Eq0 = 0.f, Eq1 = 0.f;
            float t00 = 0.f, t01 = 0.f, t02 = 0.f;
            float t10 = 0.f, t11 = 0.f, t12 = 0.f;
#pragma unroll
            for (int js = 0; js < 4; ++js) {
                const int jj = (u << 2) + js;
                const float4 bj = s_box[jj];
                const float4 ax = s_aux[jj];   // {area_j*ln2, e0, e1, e2}
                {   // row 0
                    float x1 = fmaxf(bx0.x, bj.x), y1 = fmaxf(bx0.y, bj.y);
                    float x2 = fminf(bx0.z, bj.z), y2 = fminf(bx0.w, bj.w);
                    float w = fmaxf(x2 - x1, 0.f), h = fmaxf(y2 - y1, 0.f);
                    float inter = w * h;
                    float uni = fmaf(inter, -INV_L2E, ar0 + ax.x); // ln2*union
                    float E = EXP2F(inter * __builtin_amdgcn_rcpf(uni));
                    Eq0 += E;
                    t00 = fmaf(E, ax.y, t00);
                    t01 = fmaf(E, ax.z, t01);
                    t02 = fmaf(E, ax.w, t02);
                }
                {   // row 1
                    float x1 = fmaxf(bx1.x, bj.x), y1 = fmaxf(bx1.y, bj.y);
                    float x2 = fminf(bx1.z, bj.z), y2 = fminf(bx1.w, bj.w);
                    float w = fmaxf(x2 - x1, 0.f), h = fmaxf(y2 - y1, 0.f);
                    float inter = w * h;
                    float uni = fmaf(inter, -INV_L2E, ar1 + ax.x);
                    float E = EXP2F(inter * __builtin_amdgcn_rcpf(uni));
                    Eq1 += E;
                    t10 = fmaf(E, ax.y, t10);
                    t11 = fmaf(E, ax.z, t11);
                    t12 = fmaf(E, ax.w, t12);
                }
            }
            // fold quad into running totals (per row, per class)
            accd[0][0] = fmaf(g0, Eq0, accd[0][0]);
            accd[0][1] = fmaf(g1, Eq0, accd[0][1]);
            accd[0][2] = fmaf(g2, Eq0, accd[0][2]);
            accn[0][0] = fmaf(g0, t00, accn[0][0]);
            accn[0][1] = fmaf(g1, t01, accn[0][1]);
            accn[0][2] = fmaf(g2, t02, accn[0][2]);
            accd[1][0] = fmaf(g0, Eq1, accd[1][0]);
            accd[1][1] = fmaf(g1, Eq1, accd[1][1]);
            accd[1][2] = fmaf(g2, Eq1, accd[1][2]);
            accn[1][0] = fmaf(g0, t10, accn[1][0]);
            accn[1][1] = fmaf(g1, t11, accn[1][1]);
            accn[1][2] = fmaf(g2, t12, accn[1][2]);
        }
    }

    // ---- reduce the 4 q-values (lane bits 4,5) inside each wave ----
    const int wv = t >> 6, lane = t & 63;
#pragma unroll
    for (int k = 0; k < 2; ++k)
#pragma unroll
        for (int c = 0; c < C_; ++c) {
            float nv = accn[k][c], dv = accd[k][c];
            nv += __shfl_xor(nv, 16); dv += __shfl_xor(dv, 16);
            nv += __shfl_xor(nv, 32); dv += __shfl_xor(dv, 32);
            if (lane < 16) s_red[wv][(lane << 1) + k][c] = make_float2(nv, dv);
        }
#pragma unroll
    for (int off = 1; off < 64; off <<= 1) {
        sS0 += __shfl_xor(sS0, off);
        sS1 += __shfl_xor(sS1, off);
        sS2 += __shfl_xor(sS2, off);
    }
    if (lane == 0) { s_Sp[wv][0] = sS0; s_Sp[wv][1] = sS1; s_Sp[wv][2] = sS2; }
    __syncthreads();

    // ---- final: 96 (row,c) outputs per block ----
    if (t < C_ * ROWBLK) {
        const int c = t >> 5, row = t & 31;
        float num = 0.f, den = 0.f, S = 0.f;
#pragma unroll
        for (int w = 0; w < 8; ++w) {
            float2 v = s_red[w][row][c];
            num += v.x; den += v.y;
            S += s_Sp[w][c];
        }
        const int n = rowblk * ROWBLK + row;
        out[(b * AC_ + (n & 3) * C_ + c) * HW_ + (n >> 2)] = num / (den * S);
    }
}

extern "C" void kernel_launch(void* const* d_in, const int* in_sizes, int n_in,
                              void* d_out, int out_size, void* d_ws, size_t ws_size,
                              hipStream_t stream) {
    (void)d_ws; (void)ws_size;
    const float* scores = (const float*)d_in[0];
    const float* bbox   = (const float*)d_in[1];
    const float* pp     = (const float*)d_in[2];
    const float* dec    = (const float*)d_in[3];
    k_fused<<<MAINBLKS + CPBLKS, 512, 0, stream>>>(
        scores, pp, dec, bbox, (float*)d_out);
}